// Round 2
// baseline (307.152 us; speedup 1.0000x reference)
//
#include <hip/hip_runtime.h>
#include <stdint.h>

#define B_  16
#define C_  512
#define S_  1024
#define O3_ 1536
#define NSAMP (C_*S_)   // 524288 elements per sample

typedef __bf16 bf16x8 __attribute__((ext_vector_type(8)));
typedef float  f32x4  __attribute__((ext_vector_type(4)));

__device__ __forceinline__ float bf2f(uint16_t u){ return __uint_as_float(((uint32_t)u)<<16); }
__device__ __forceinline__ uint16_t f2bf(float f){
  uint32_t u = __float_as_uint(f);
  uint32_t r = u + 0x7fffu + ((u>>16)&1u);   // RNE
  return (uint16_t)(r>>16);
}
__device__ __forceinline__ float wsum(float v){
  #pragma unroll
  for(int o=32;o;o>>=1) v += __shfl_xor(v,o,64);
  return v;
}
__device__ __forceinline__ float wmax(float v){
  #pragma unroll
  for(int o=32;o;o>>=1) v = fmaxf(v, __shfl_xor(v,o,64));
  return v;
}
__device__ __forceinline__ void gload16(const void* g, void* l){
  __builtin_amdgcn_global_load_lds(
      (__attribute__((address_space(1))) void*)g,
      (__attribute__((address_space(3))) void*)l, 16, 0, 0);
}

// ---------- dtype detector: even-index uint16s of fp32 data have random exponents ----------
__global__ __launch_bounds__(256) void detect_k(const uint16_t* __restrict__ x,
                                                int* __restrict__ flag){
  __shared__ int sh[4];
  int cnt = 0;
  for(int i=threadIdx.x; i<32768; i+=256){
    uint32_t e = (x[2*i] >> 7) & 0xffu;    // bf16 exponent field of even elements
    cnt += (e >= 132) ? 1 : 0;             // |v| >= 32: never for N(0,1) bf16 data
  }
  #pragma unroll
  for(int o=32;o;o>>=1) cnt += __shfl_xor(cnt,o,64);
  const int lane = threadIdx.x & 63, w = threadIdx.x >> 6;
  if (lane==0) sh[w] = cnt;
  __syncthreads();
  if (threadIdx.x==0) *flag = (sh[0]+sh[1]+sh[2]+sh[3] > 4096) ? 1 : 0;  // 1 => fp32 inputs
}

// ---------- normalize any input to a bf16 copy (n must be a multiple of 8) ----------
__global__ __launch_bounds__(256) void conv_k(const void* __restrict__ src,
                                              uint16_t* __restrict__ dst, int n,
                                              const int* __restrict__ flag){
  const int f = *flag;
  const int idx = (blockIdx.x*256 + threadIdx.x)*8;
  if (idx >= n) return;
  if (f){
    const float* s = (const float*)src;
    float4 v0 = *(const float4*)(s + idx);
    float4 v1 = *(const float4*)(s + idx + 4);
    ushort4 a, b;
    a.x=f2bf(v0.x); a.y=f2bf(v0.y); a.z=f2bf(v0.z); a.w=f2bf(v0.w);
    b.x=f2bf(v1.x); b.y=f2bf(v1.y); b.z=f2bf(v1.z); b.w=f2bf(v1.w);
    *(ushort4*)(dst + idx)     = a;
    *(ushort4*)(dst + idx + 4) = b;
  } else {
    *(uint4*)(dst + idx) = *(const uint4*)((const uint16_t*)src + idx);
  }
}

// ---------- final emit: fp32 [B,C,S] result -> d_out in detected dtype ----------
__global__ __launch_bounds__(256) void emit_k(const float* __restrict__ outF,
                                              void* __restrict__ dout,
                                              const int* __restrict__ flag){
  const int f = *flag;
  const size_t idx = ((size_t)blockIdx.x*256 + threadIdx.x)*4;
  float4 v = *(const float4*)(outF + idx);
  if (f){
    *(float4*)((float*)dout + idx) = v;
  } else {
    ushort4 o; o.x=f2bf(v.x); o.y=f2bf(v.y); o.z=f2bf(v.z); o.w=f2bf(v.w);
    *(ushort4*)((uint16_t*)dout + idx) = o;
  }
}

// ---------------- GroupNorm stats (2-stage, no atomics) ----------------
__global__ __launch_bounds__(256) void gn_partial(const uint16_t* __restrict__ x,
                                                  float2* __restrict__ part){
  const int b = blockIdx.x >> 6, j = blockIdx.x & 63;
  const uint16_t* xs = x + (size_t)b*NSAMP + j*8192;
  float s=0.f, s2=0.f;
  #pragma unroll
  for(int i=0;i<4;i++){
    uint4 p = ((const uint4*)xs)[i*256 + threadIdx.x];
    uint32_t uu[4] = {p.x,p.y,p.z,p.w};
    #pragma unroll
    for(int q=0;q<4;q++){
      float f0 = __uint_as_float(uu[q]<<16);
      float f1 = __uint_as_float(uu[q] & 0xffff0000u);
      s += f0 + f1; s2 += f0*f0 + f1*f1;
    }
  }
  s = wsum(s); s2 = wsum(s2);
  __shared__ float rs[4], rq[4];
  const int lane = threadIdx.x & 63, w = threadIdx.x >> 6;
  if (lane==0){ rs[w]=s; rq[w]=s2; }
  __syncthreads();
  if (threadIdx.x==0)
    part[blockIdx.x] = make_float2(rs[0]+rs[1]+rs[2]+rs[3], rq[0]+rq[1]+rq[2]+rq[3]);
}

__global__ __launch_bounds__(64) void gn_final(const float2* __restrict__ part,
                                               float2* __restrict__ stats){
  const int b = blockIdx.x, lane = threadIdx.x;
  float2 p = part[b*64 + lane];
  float s = wsum(p.x), s2 = wsum(p.y);
  if (lane==0){
    const float n = 1.f/(float)NSAMP;
    float mean = s*n;
    float var = s2*n - mean*mean;
    stats[b] = make_float2(mean, rsqrtf(var + 1e-5f));
  }
}

// ---- GN apply + transpose [B,C,S] -> hT [B,S,C] bf16 ----
__global__ __launch_bounds__(256) void gn_apply_t(const uint16_t* __restrict__ x,
    const uint16_t* __restrict__ gw, const uint16_t* __restrict__ gb,
    const float2* __restrict__ stats, uint16_t* __restrict__ hT){
  __shared__ float tile[64][65];
  const int b = blockIdx.z, c0 = blockIdx.y<<6, s0 = blockIdx.x<<6;
  const float2 st = stats[b];
  const int tc = threadIdx.x >> 6, tl = threadIdx.x & 63;
  #pragma unroll
  for(int r=0;r<16;r++){
    int cl = r*4 + tc;
    tile[cl][tl] = bf2f(x[((size_t)b*C_ + c0+cl)*S_ + s0 + tl]);
  }
  __syncthreads();
  const float wv = bf2f(gw[c0+tl]) * st.y;
  const float bv = bf2f(gb[c0+tl]);
  const float mn = st.x;
  #pragma unroll
  for(int r=0;r<16;r++){
    int sl = r*4 + tc;
    float v = (tile[tl][sl] - mn)*wv + bv;
    hT[((size_t)b*S_ + s0+sl)*C_ + c0 + tl] = f2bf(v);
  }
}

// ---- V transpose: qkv[b,k,1024+c] -> Vt[b,c,k] ----
__global__ __launch_bounds__(256) void transp_v(const uint16_t* __restrict__ qkv,
                                                uint16_t* __restrict__ Vt){
  __shared__ uint32_t tile[64][65];
  const int b = blockIdx.z, c0 = blockIdx.y<<6, k0 = blockIdx.x<<6;
  const int tc = threadIdx.x >> 6, tl = threadIdx.x & 63;
  const uint16_t* src = qkv + (size_t)b*S_*O3_ + 1024;
  #pragma unroll
  for(int r=0;r<16;r++){
    int kl = r*4 + tc;
    tile[kl][tl] = src[(size_t)(k0+kl)*O3_ + c0 + tl];
  }
  __syncthreads();
  uint16_t* dst = Vt + (size_t)b*C_*S_;
  #pragma unroll
  for(int r=0;r<16;r++){
    int cl = r*4 + tc;
    dst[(size_t)(c0+cl)*S_ + k0 + tl] = (uint16_t)tile[tl][cl];
  }
}

// ---------------- 128x128 MFMA GEMM, C = A * Bt^T (both K-major) ----------------
// TRANSRES epilogue: row=(b*1024+s), col=channel -> outF[b,col,s] = acc+bias+xres (fp32)
template<bool OUTF32, bool HASBIAS, bool TRANSRES>
__global__ __launch_bounds__(256)
void gemm_bt(const uint16_t* __restrict__ A, const uint16_t* __restrict__ Bt,
             void* __restrict__ Cp, const uint16_t* __restrict__ bias,
             const uint16_t* __restrict__ xres,
             int lda, int ldb, int ldc, int K,
             long long sA, long long sB, long long sC)
{
  __shared__ uint16_t As[128*64];
  __shared__ uint16_t Bs[128*64];
  const int tid = threadIdx.x;
  const int lane = tid & 63, w = tid >> 6;
  const int quad = lane >> 4, lm = lane & 15;
  const int m0 = blockIdx.y << 7, n0 = blockIdx.x << 7;
  A  += (size_t)blockIdx.z * sA;
  Bt += (size_t)blockIdx.z * sB;

  f32x4 acc[4][4];
  #pragma unroll
  for(int i=0;i<4;i++)
    #pragma unroll
    for(int j=0;j<4;j++) acc[i][j] = (f32x4){0.f,0.f,0.f,0.f};

  const int wm = (w & 1) << 6, wn = (w >> 1) << 6;
  const uint16_t* ga = A  + (size_t)(m0 + (tid>>3))*lda + (tid&7)*8;
  const uint16_t* gb = Bt + (size_t)(n0 + (tid>>3))*ldb + (tid&7)*8;
  uint16_t* sa = &As[tid*8];
  uint16_t* sb = &Bs[tid*8];

  for(int k0=0;k0<K;k0+=64){
    #pragma unroll
    for(int i=0;i<4;i++){
      gload16(ga + (size_t)(i*32)*lda + k0, sa + i*2048);
      gload16(gb + (size_t)(i*32)*ldb + k0, sb + i*2048);
    }
    __syncthreads();
    #pragma unroll
    for(int kk=0;kk<64;kk+=32){
      bf16x8 av[4], bv[4];
      #pragma unroll
      for(int i=0;i<4;i++) av[i] = *(const bf16x8*)&As[(wm + i*16 + lm)*64 + kk + quad*8];
      #pragma unroll
      for(int j=0;j<4;j++) bv[j] = *(const bf16x8*)&Bs[(wn + j*16 + lm)*64 + kk + quad*8];
      #pragma unroll
      for(int i=0;i<4;i++)
        #pragma unroll
        for(int j=0;j<4;j++)
          acc[i][j] = __builtin_amdgcn_mfma_f32_16x16x32_bf16(av[i], bv[j], acc[i][j], 0,0,0);
    }
    __syncthreads();
  }

  if (TRANSRES){
    float* outp = (float*)Cp;
    #pragma unroll
    for(int j=0;j<4;j++){
      const int col = n0 + wn + j*16 + lm;                  // channel
      const float bvv = HASBIAS ? bf2f(bias[col]) : 0.f;
      #pragma unroll
      for(int i=0;i<4;i++){
        const int rb = m0 + wm + i*16 + (quad<<2);
        #pragma unroll
        for(int r=0;r<4;r++){
          const int row = rb + r;                           // b*1024 + s
          const int bb = row >> 10, ss = row & 1023;
          const size_t idx = ((size_t)bb*C_ + col)*S_ + ss;
          outp[idx] = acc[i][j][r] + bvv + bf2f(xres[idx]);
        }
      }
    }
  } else {
    const size_t cb = (size_t)blockIdx.z * (size_t)sC;
    #pragma unroll
    for(int j=0;j<4;j++){
      const int col = n0 + wn + j*16 + lm;
      const float bvv = HASBIAS ? bf2f(bias[col]) : 0.f;
      #pragma unroll
      for(int i=0;i<4;i++){
        const int rb = m0 + wm + i*16 + (quad<<2);
        #pragma unroll
        for(int r=0;r<4;r++){
          const int row = rb + r;
          const float v = acc[i][j][r] + bvv;
          if (OUTF32) ((float*)Cp)[cb + (size_t)row*ldc + col] = v;
          else ((uint16_t*)Cp)[cb + (size_t)row*ldc + col] = f2bf(v);
        }
      }
    }
  }
}

// ---- softmax; writes bf16 P overlaid in-place (row stride 2048 bf16 elems) ----
__global__ __launch_bounds__(256) void softmax_k(float* __restrict__ sc){
  const int row = blockIdx.x;
  float* srow = sc + (size_t)row * 1024;
  const int t = threadIdx.x, lane = t & 63, w = t >> 6;
  __shared__ float red[4];
  float4 v = ((const float4*)srow)[t];
  const float scale = 0.044194173824159216f; // 512^-0.5
  float a = v.x*scale, b = v.y*scale, c = v.z*scale, d = v.w*scale;
  float mx = fmaxf(fmaxf(a,b),fmaxf(c,d));
  mx = wmax(mx);
  if (lane==0) red[w] = mx;
  __syncthreads();
  mx = fmaxf(fmaxf(red[0],red[1]),fmaxf(red[2],red[3]));
  float e0=__expf(a-mx), e1=__expf(b-mx), e2=__expf(c-mx), e3=__expf(d-mx);
  float s = wsum(e0+e1+e2+e3);
  __syncthreads();
  if (lane==0) red[w] = s;
  __syncthreads();
  const float inv = 1.f/(red[0]+red[1]+red[2]+red[3]);
  ushort4 o;
  o.x = f2bf(e0*inv); o.y = f2bf(e1*inv); o.z = f2bf(e2*inv); o.w = f2bf(e3*inv);
  ((ushort4*)srow)[t] = o;
}

extern "C" void kernel_launch(void* const* d_in, const int* in_sizes, int n_in,
                              void* d_out, int out_size, void* d_ws, size_t ws_size,
                              hipStream_t stream){
  char* ws = (char*)d_ws;
  int*      flag  = (int*)ws;                                  // 4 B
  float2*   part  = (float2*)(ws + 4096);                      // 8 KB
  float2*   stats = (float2*)(ws + 16384);                     // 128 B
  uint16_t* xb    = (uint16_t*)(ws + 65536);                   // 16.8 MB  [B,C,S] bf16
  uint16_t* gnwb  = (uint16_t*)(ws + 16842752);
  uint16_t* gnbb  = (uint16_t*)(ws + 16846848);
  uint16_t* qkvbb = (uint16_t*)(ws + 16850944);
  uint16_t* projbb= (uint16_t*)(ws + 16855040);
  uint16_t* qkvwb = (uint16_t*)(ws + 16859136);                // 1.57 MB
  uint16_t* projwb= (uint16_t*)(ws + 18432000);                // 0.52 MB
  uint16_t* hT    = (uint16_t*)(ws + 18956288);                // 16.8 MB  [16384,512]
  uint16_t* qkv   = (uint16_t*)(ws + 35733504);                // 50.3 MB  [16384,1536]
  float*    sc    = (float*)   (ws + 86065152);                // 67.1 MB  [16,1024,1024]
  uint16_t* Vt    = (uint16_t*)(ws + 153174016);               // 16.8 MB  [16,512,1024]
  float*    outF  = sc;   // overlay: sc is dead after the PV GEMM consumes P
  // total ws use ~170 MB

  hipLaunchKernelGGL(detect_k, dim3(1), dim3(256), 0, stream,
                     (const uint16_t*)d_in[0], flag);
  // normalize all inputs to bf16
  hipLaunchKernelGGL(conv_k, dim3((8388608+2047)/2048), dim3(256), 0, stream, d_in[0], xb,     8388608, flag);
  hipLaunchKernelGGL(conv_k, dim3(1),   dim3(256), 0, stream, d_in[1], gnwb,   512,    flag);
  hipLaunchKernelGGL(conv_k, dim3(1),   dim3(256), 0, stream, d_in[2], gnbb,   512,    flag);
  hipLaunchKernelGGL(conv_k, dim3(384), dim3(256), 0, stream, d_in[3], qkvwb,  786432, flag);
  hipLaunchKernelGGL(conv_k, dim3(1),   dim3(256), 0, stream, d_in[4], qkvbb,  1536,   flag);
  hipLaunchKernelGGL(conv_k, dim3(128), dim3(256), 0, stream, d_in[5], projwb, 262144, flag);
  hipLaunchKernelGGL(conv_k, dim3(1),   dim3(256), 0, stream, d_in[6], projbb, 512,    flag);

  hipLaunchKernelGGL(gn_partial, dim3(1024), dim3(256), 0, stream, xb, part);
  hipLaunchKernelGGL(gn_final,   dim3(16),   dim3(64),  0, stream, part, stats);
  hipLaunchKernelGGL(gn_apply_t, dim3(16,8,16), dim3(256), 0, stream, xb, gnwb, gnbb, stats, hT);

  // QKV: [16384,512] x [1536,512]^T -> [16384,1536] + bias
  hipLaunchKernelGGL((gemm_bt<false,true,false>), dim3(12,128,1), dim3(256), 0, stream,
      hT, qkvwb, (void*)qkv, qkvbb, (const uint16_t*)nullptr,
      512, 512, 1536, 512, 0LL, 0LL, 0LL);

  // scores = Q K^T (fp32), per batch
  hipLaunchKernelGGL((gemm_bt<true,false,false>), dim3(8,8,16), dim3(256), 0, stream,
      qkv, qkv+512, (void*)sc, (const uint16_t*)nullptr, (const uint16_t*)nullptr,
      O3_, O3_, S_, 512, (long long)S_*O3_, (long long)S_*O3_, (long long)S_*S_);

  hipLaunchKernelGGL(softmax_k, dim3(B_*S_), dim3(256), 0, stream, sc);
  hipLaunchKernelGGL(transp_v,  dim3(16,8,16), dim3(256), 0, stream, qkv, Vt);

  // attn_out = P V, per batch: [1024,1024(lda 2048 overlay)] x [512,1024]^T -> hT
  hipLaunchKernelGGL((gemm_bt<false,false,false>), dim3(4,8,16), dim3(256), 0, stream,
      (const uint16_t*)sc, Vt, (void*)hT, (const uint16_t*)nullptr, (const uint16_t*)nullptr,
      2048, S_, 512, 1024, (long long)S_*2048, (long long)C_*S_, (long long)S_*C_);

  // proj + bias + residual + transpose -> outF (fp32, [B,C,S])
  hipLaunchKernelGGL((gemm_bt<false,true,true>), dim3(4,128,1), dim3(256), 0, stream,
      hT, projwb, (void*)outF, projbb, xb, 512, 512, 0, 512, 0LL, 0LL, 0LL);

  // emit in detected dtype
  hipLaunchKernelGGL(emit_k, dim3(8388608/1024), dim3(256), 0, stream, outF, d_out, flag);
}

// Round 3
// 285.828 us; speedup vs baseline: 1.0746x; 1.0746x over previous
//
#include <hip/hip_runtime.h>
#include <stdint.h>

#define B_  16
#define C_  512
#define S_  1024
#define NSAMP (C_*S_)   // 524288 elements per sample

typedef __bf16 bf16x8 __attribute__((ext_vector_type(8)));
typedef float  f32x4  __attribute__((ext_vector_type(4)));

__device__ __forceinline__ float bf2f(uint16_t u){ return __uint_as_float(((uint32_t)u)<<16); }
__device__ __forceinline__ uint16_t f2bf(float f){
  uint32_t u = __float_as_uint(f);
  uint32_t r = u + 0x7fffu + ((u>>16)&1u);   // RNE
  return (uint16_t)(r>>16);
}
__device__ __forceinline__ float wsum(float v){
  #pragma unroll
  for(int o=32;o;o>>=1) v += __shfl_xor(v,o,64);
  return v;
}
__device__ __forceinline__ float wmax(float v){
  #pragma unroll
  for(int o=32;o;o>>=1) v = fmaxf(v, __shfl_xor(v,o,64));
  return v;
}
__device__ __forceinline__ void gload16(const void* g, void* l){
  __builtin_amdgcn_global_load_lds(
      (__attribute__((address_space(1))) void*)g,
      (__attribute__((address_space(3))) void*)l, 16, 0, 0);
}

// ---------- dtype detector ----------
__global__ __launch_bounds__(256) void detect_k(const uint16_t* __restrict__ x,
                                                int* __restrict__ flag){
  __shared__ int sh[4];
  int cnt = 0;
  for(int i=threadIdx.x; i<32768; i+=256){
    uint32_t e = (x[2*i] >> 7) & 0xffu;
    cnt += (e >= 132) ? 1 : 0;
  }
  #pragma unroll
  for(int o=32;o;o>>=1) cnt += __shfl_xor(cnt,o,64);
  const int lane = threadIdx.x & 63, w = threadIdx.x >> 6;
  if (lane==0) sh[w] = cnt;
  __syncthreads();
  if (threadIdx.x==0) *flag = (sh[0]+sh[1]+sh[2]+sh[3] > 4096) ? 1 : 0;  // 1 => fp32
}

// ---------- fused: x -> bf16 copy + GN partial sums (stats from pre-rounded values) ----------
__global__ __launch_bounds__(256) void conv_x_gn(const void* __restrict__ src,
                                                 uint16_t* __restrict__ xb,
                                                 float2* __restrict__ part,
                                                 const int* __restrict__ flag){
  const int f = *flag;
  const size_t base = (size_t)blockIdx.x * 8192;
  float s = 0.f, s2 = 0.f;
  if (f){
    const float4* sp = (const float4*)((const float*)src + base);
    ushort4* dp = (ushort4*)(xb + base);
    #pragma unroll
    for(int i=0;i<8;i++){
      float4 v = sp[i*256 + threadIdx.x];
      s  += v.x + v.y + v.z + v.w;
      s2 += v.x*v.x + v.y*v.y + v.z*v.z + v.w*v.w;
      ushort4 o; o.x=f2bf(v.x); o.y=f2bf(v.y); o.z=f2bf(v.z); o.w=f2bf(v.w);
      dp[i*256 + threadIdx.x] = o;
    }
  } else {
    const uint4* sp = (const uint4*)((const uint16_t*)src + base);
    uint4* dp = (uint4*)(xb + base);
    #pragma unroll
    for(int i=0;i<4;i++){
      uint4 p = sp[i*256 + threadIdx.x];
      dp[i*256 + threadIdx.x] = p;
      uint32_t uu[4] = {p.x,p.y,p.z,p.w};
      #pragma unroll
      for(int q=0;q<4;q++){
        float f0 = __uint_as_float(uu[q]<<16);
        float f1 = __uint_as_float(uu[q] & 0xffff0000u);
        s += f0 + f1; s2 += f0*f0 + f1*f1;
      }
    }
  }
  s = wsum(s); s2 = wsum(s2);
  __shared__ float rs[4], rq[4];
  const int lane = threadIdx.x & 63, w = threadIdx.x >> 6;
  if (lane==0){ rs[w]=s; rq[w]=s2; }
  __syncthreads();
  if (threadIdx.x==0)
    part[blockIdx.x] = make_float2(rs[0]+rs[1]+rs[2]+rs[3], rq[0]+rq[1]+rq[2]+rq[3]);
}

// ---------- all params -> bf16 copies, one kernel ----------
__device__ __forceinline__ void convseg(const void* src, uint16_t* dst, int n, int f, int t){
  const int idx = t*8;
  if (idx >= n) return;
  if (f){
    const float* s = (const float*)src;
    float4 v0 = *(const float4*)(s + idx);
    float4 v1 = *(const float4*)(s + idx + 4);
    ushort4 a, b;
    a.x=f2bf(v0.x); a.y=f2bf(v0.y); a.z=f2bf(v0.z); a.w=f2bf(v0.w);
    b.x=f2bf(v1.x); b.y=f2bf(v1.y); b.z=f2bf(v1.z); b.w=f2bf(v1.w);
    *(ushort4*)(dst + idx)     = a;
    *(ushort4*)(dst + idx + 4) = b;
  } else {
    *(uint4*)(dst + idx) = *(const uint4*)((const uint16_t*)src + idx);
  }
}
__global__ __launch_bounds__(256) void param_conv(
    const void* qkvw, const void* projw, const void* gnw, const void* gnb,
    const void* qkvb, const void* projb,
    uint16_t* qkvwb, uint16_t* projwb, uint16_t* gnwb, uint16_t* gnbb,
    uint16_t* qkvbb, uint16_t* projbb, const int* __restrict__ flag){
  const int f = *flag;
  const int bid = blockIdx.x, t = threadIdx.x;
  if (bid < 384){
    const size_t off = (size_t)bid*2048;
    convseg((const char*)qkvw + off*(f?4:2), qkvwb + off, 2048, f, t);
  } else if (bid < 512){
    const size_t off = (size_t)(bid-384)*2048;
    convseg((const char*)projw + off*(f?4:2), projwb + off, 2048, f, t);
  } else {
    convseg(gnw,   gnwb,   512,  f, t);
    convseg(gnb,   gnbb,   512,  f, t);
    convseg(qkvb,  qkvbb,  1536, f, t);
    convseg(projb, projbb, 512,  f, t);
  }
}

// ---- GN apply + transpose [B,C,S] -> hT [B,S,C] bf16; stats reduced inline ----
__global__ __launch_bounds__(256) void gn_apply_t(const uint16_t* __restrict__ x,
    const uint16_t* __restrict__ gw, const uint16_t* __restrict__ gb,
    const float2* __restrict__ part, uint16_t* __restrict__ hT){
  __shared__ float tile[64][65];
  const int b = blockIdx.z, c0 = blockIdx.y<<6, s0 = blockIdx.x<<6;
  const int tc = threadIdx.x >> 6, tl = threadIdx.x & 63;
  float2 p = part[b*64 + tl];
  float s = wsum(p.x), s2 = wsum(p.y);
  const float ninv = 1.f/(float)NSAMP;
  const float mn = s*ninv;
  const float rstd = rsqrtf(s2*ninv - mn*mn + 1e-5f);
  #pragma unroll
  for(int r=0;r<16;r++){
    int cl = r*4 + tc;
    tile[cl][tl] = bf2f(x[((size_t)b*C_ + c0+cl)*S_ + s0 + tl]);
  }
  __syncthreads();
  const float wv = bf2f(gw[c0+tl]) * rstd;
  const float bv = bf2f(gb[c0+tl]);
  #pragma unroll
  for(int r=0;r<16;r++){
    int sl = r*4 + tc;
    float v = (tile[tl][sl] - mn)*wv + bv;
    hT[((size_t)b*S_ + s0+sl)*C_ + c0 + tl] = f2bf(v);
  }
}

// ---------------- 128x128 MFMA GEMM, C = A * Bt^T (both K-major), XCD-swizzled ----------------
template<bool HASBIAS, bool BIASROW, bool OUTDYN, bool HASRES>
__global__ __launch_bounds__(256)
void gemm_bt(const uint16_t* __restrict__ A, const uint16_t* __restrict__ Bt,
             void* __restrict__ Cp, const uint16_t* __restrict__ bias,
             const uint16_t* __restrict__ xres, const int* __restrict__ flag,
             int lda, int ldb, int ldc, int K,
             long long sA, long long sB, long long sC)
{
  __shared__ uint16_t As[128*64];
  __shared__ uint16_t Bs[128*64];
  // XCD swizzle: blocks sharing an A row-tile (same rr, all bx) get consecutive
  // lin ids 8 apart -> same XCD under lin%8 round-robin, same L2.
  const int lin = (blockIdx.z * gridDim.y + blockIdx.y) * gridDim.x + blockIdx.x;
  const int xcd = lin & 7, t = lin >> 3;
  const int bx  = t % gridDim.x;
  const int rr  = (t / gridDim.x) * 8 + xcd;
  const int by  = rr % gridDim.y;
  const int bz  = rr / gridDim.y;

  const int tid = threadIdx.x;
  const int lane = tid & 63, w = tid >> 6;
  const int quad = lane >> 4, lm = lane & 15;
  const int m0 = by << 7, n0 = bx << 7;
  A  += (size_t)bz * sA;
  Bt += (size_t)bz * sB;

  f32x4 acc[4][4];
  #pragma unroll
  for(int i=0;i<4;i++)
    #pragma unroll
    for(int j=0;j<4;j++) acc[i][j] = (f32x4){0.f,0.f,0.f,0.f};

  const int wm = (w & 1) << 6, wn = (w >> 1) << 6;
  const uint16_t* ga = A  + (size_t)(m0 + (tid>>3))*lda + (tid&7)*8;
  const uint16_t* gb = Bt + (size_t)(n0 + (tid>>3))*ldb + (tid&7)*8;
  uint16_t* sa = &As[tid*8];
  uint16_t* sb = &Bs[tid*8];

  for(int k0=0;k0<K;k0+=64){
    #pragma unroll
    for(int i=0;i<4;i++){
      gload16(ga + (size_t)(i*32)*lda + k0, sa + i*2048);
      gload16(gb + (size_t)(i*32)*ldb + k0, sb + i*2048);
    }
    __syncthreads();
    #pragma unroll
    for(int kk=0;kk<64;kk+=32){
      bf16x8 av[4], bv[4];
      #pragma unroll
      for(int i=0;i<4;i++) av[i] = *(const bf16x8*)&As[(wm + i*16 + lm)*64 + kk + quad*8];
      #pragma unroll
      for(int j=0;j<4;j++) bv[j] = *(const bf16x8*)&Bs[(wn + j*16 + lm)*64 + kk + quad*8];
      #pragma unroll
      for(int i=0;i<4;i++)
        #pragma unroll
        for(int j=0;j<4;j++)
          acc[i][j] = __builtin_amdgcn_mfma_f32_16x16x32_bf16(av[i], bv[j], acc[i][j], 0,0,0);
    }
    __syncthreads();
  }

  const int f = OUTDYN ? *flag : 0;
  const size_t cb = (size_t)bz * (size_t)sC;
  #pragma unroll
  for(int j=0;j<4;j++){
    const int col = n0 + wn + j*16 + lm;
    const float cbias = (HASBIAS && !BIASROW) ? bf2f(bias[col]) : 0.f;
    #pragma unroll
    for(int i=0;i<4;i++){
      const int rb = m0 + wm + i*16 + (quad<<2);
      #pragma unroll
      for(int r=0;r<4;r++){
        const int row = rb + r;
        float v = acc[i][j][r] + cbias;
        if (HASBIAS && BIASROW) v += bf2f(bias[row]);
        const size_t idx = cb + (size_t)row*ldc + col;
        if (HASRES) v += bf2f(xres[idx]);
        if (OUTDYN && f) ((float*)Cp)[idx] = v;
        else             ((uint16_t*)Cp)[idx] = f2bf(v);
      }
    }
  }
}

// ---- softmax over bf16 score rows, in place ----
__global__ __launch_bounds__(256) void softmax_k(uint16_t* __restrict__ sc){
  uint16_t* srow = sc + (size_t)blockIdx.x * 1024;
  const int t = threadIdx.x, lane = t & 63, w = t >> 6;
  __shared__ float red[4];
  ushort4 v = ((const ushort4*)srow)[t];
  const float scale = 0.044194173824159216f; // 512^-0.5
  float a = bf2f(v.x)*scale, b = bf2f(v.y)*scale, c = bf2f(v.z)*scale, d = bf2f(v.w)*scale;
  float mx = fmaxf(fmaxf(a,b),fmaxf(c,d));
  mx = wmax(mx);
  if (lane==0) red[w] = mx;
  __syncthreads();
  mx = fmaxf(fmaxf(red[0],red[1]),fmaxf(red[2],red[3]));
  float e0=__expf(a-mx), e1=__expf(b-mx), e2=__expf(c-mx), e3=__expf(d-mx);
  float s = wsum(e0+e1+e2+e3);
  __syncthreads();
  if (lane==0) red[w] = s;
  __syncthreads();
  const float inv = 1.f/(red[0]+red[1]+red[2]+red[3]);
  ushort4 o;
  o.x = f2bf(e0*inv); o.y = f2bf(e1*inv); o.z = f2bf(e2*inv); o.w = f2bf(e3*inv);
  ((ushort4*)srow)[t] = o;
}

extern "C" void kernel_launch(void* const* d_in, const int* in_sizes, int n_in,
                              void* d_out, int out_size, void* d_ws, size_t ws_size,
                              hipStream_t stream){
  char* ws = (char*)d_ws;
  int*      flag  = (int*)ws;                         // 4 B
  float2*   part  = (float2*)(ws + 4096);             // 8 KB (1024 float2)
  uint16_t* gnwb  = (uint16_t*)(ws + 16384);
  uint16_t* gnbb  = (uint16_t*)(ws + 17408);
  uint16_t* qkvbb = (uint16_t*)(ws + 18432);
  uint16_t* projbb= (uint16_t*)(ws + 21504);
  uint16_t* qkvwb = (uint16_t*)(ws + 32768);          // 1.57 MB
  uint16_t* projwb= (uint16_t*)(ws + 1605632);        // 0.52 MB
  uint16_t* xb    = (uint16_t*)(ws + 4194304);        // 16.8 MB [B,C,S]
  uint16_t* hT    = (uint16_t*)(ws + 20971520);       // 16.8 MB [16384,512]; reused for attn
  uint16_t* qk    = (uint16_t*)(ws + 37748736);       // 33.6 MB [16384,1024] (Q|K)
  uint16_t* sc    = (uint16_t*)(ws + 71303168);       // 33.6 MB [16,1024,1024]
  uint16_t* Vt    = (uint16_t*)(ws + 104857600);      // 16.8 MB [16,512,1024]
  // end 121.6 MB

  hipLaunchKernelGGL(detect_k, dim3(1), dim3(256), 0, stream,
                     (const uint16_t*)d_in[0], flag);
  hipLaunchKernelGGL(param_conv, dim3(513), dim3(256), 0, stream,
                     d_in[3], d_in[5], d_in[1], d_in[2], d_in[4], d_in[6],
                     qkvwb, projwb, gnwb, gnbb, qkvbb, projbb, flag);
  hipLaunchKernelGGL(conv_x_gn, dim3(1024), dim3(256), 0, stream, d_in[0], xb, part, flag);
  hipLaunchKernelGGL(gn_apply_t, dim3(16,8,16), dim3(256), 0, stream, xb, gnwb, gnbb, part, hT);

  // QK: [16384,512] x [1024,512]^T -> qk[16384,1024] (+bias cols 0..1023)
  hipLaunchKernelGGL((gemm_bt<true,false,false,false>), dim3(8,128,1), dim3(256), 0, stream,
      hT, qkvwb, (void*)qk, qkvbb, (const uint16_t*)nullptr, flag,
      512, 512, 1024, 512, 0LL, 0LL, 0LL);

  // V^T: per batch [512,512] x [1024,512]^T -> Vt[b][512,1024] (+bias rows 1024..1535)
  hipLaunchKernelGGL((gemm_bt<true,true,false,false>), dim3(8,4,16), dim3(256), 0, stream,
      qkvwb + (size_t)1024*512, hT, (void*)Vt, qkvbb + 1024, (const uint16_t*)nullptr, flag,
      512, 512, 1024, 512, 0LL, (long long)S_*C_, (long long)C_*S_);

  // scores = Q K^T (bf16), per batch: [1024,512] x [1024,512]^T
  hipLaunchKernelGGL((gemm_bt<false,false,false,false>), dim3(8,8,16), dim3(256), 0, stream,
      qk, qk + 512, (void*)sc, (const uint16_t*)nullptr, (const uint16_t*)nullptr, flag,
      1024, 1024, 1024, 512, (long long)S_*1024, (long long)S_*1024, (long long)S_*S_);

  hipLaunchKernelGGL(softmax_k, dim3(B_*S_), dim3(256), 0, stream, sc);

  // attn = P V: per batch [1024,1024] x [512,1024]^T -> hT[bs,512]
  hipLaunchKernelGGL((gemm_bt<false,false,false,false>), dim3(4,8,16), dim3(256), 0, stream,
      sc, Vt, (void*)hT, (const uint16_t*)nullptr, (const uint16_t*)nullptr, flag,
      1024, 1024, 512, 1024, (long long)S_*S_, (long long)C_*S_, (long long)S_*C_);

  // out[b,c,s] = projW · attn_b^T + projb + x   (direct, coalesced, dtype via flag)
  hipLaunchKernelGGL((gemm_bt<true,true,true,true>), dim3(8,4,16), dim3(256), 0, stream,
      projwb, hT, d_out, projbb, xb, flag,
      512, 512, 1024, 512, 0LL, (long long)S_*C_, (long long)C_*S_);
}